// Round 7
// baseline (388.507 us; speedup 1.0000x reference)
//
#include <hip/hip_runtime.h>
#include <cstdint>
#include <cstddef>

// Problem constants
#define DIMN 1024
#define SEQ  2048
#define NBAT 4
#define TOKS (NBAT * SEQ)   // 8192

typedef unsigned short u16;
typedef unsigned int   u32;

typedef __bf16 bf16x8 __attribute__((ext_vector_type(8)));
typedef float  f32x4  __attribute__((ext_vector_type(4)));

#define AS1 __attribute__((address_space(1)))
#define AS3 __attribute__((address_space(3)))

// ---- helpers ----------------------------------------------------------------

__device__ __forceinline__ u16 f2b(float f) {
  union { float f; u32 u; } v; v.f = f;
  u32 r = v.u + 0x7fffu + ((v.u >> 16) & 1u);   // round-to-nearest-even
  return (u16)(r >> 16);
}

__device__ __forceinline__ float b2f(u16 b) {
  union { u32 u; float f; } v; v.u = ((u32)b) << 16;
  return v.f;
}

// tanh-form GELU (branch-free, max dev vs exact erf form ~3e-3)
__device__ __forceinline__ float gelu_fast(float x) {
  float y = 0.79788456080286536f * (x + 0.044715f * x * x * x);
  float e = __expf(2.0f * y);
  float t = 1.0f - 2.0f / (e + 1.0f);
  return 0.5f * x * (1.0f + t);
}

__device__ __forceinline__ float wave_sum(float a) {
  #pragma unroll
  for (int o = 32; o >= 1; o >>= 1) a += __shfl_xor(a, o, 64);
  return a;
}

__device__ __forceinline__ float wave_max(float a) {
  #pragma unroll
  for (int o = 32; o >= 1; o >>= 1) a = fmaxf(a, __shfl_xor(a, o, 64));
  return a;
}

__device__ __forceinline__ void unpack8(uint4 raw, float* o) {
  #pragma unroll
  for (int m = 0; m < 4; ++m) {
    u32 w = ((const u32*)&raw)[m];
    o[2 * m]     = b2f((u16)(w & 0xffff));
    o[2 * m + 1] = b2f((u16)(w >> 16));
  }
}

__device__ __forceinline__ uint4 pack8(const float* v) {
  uint4 o;
  #pragma unroll
  for (int m = 0; m < 4; ++m)
    ((u32*)&o)[m] = (u32)f2b(v[2 * m]) | ((u32)f2b(v[2 * m + 1]) << 16);
  return o;
}

// ---- prep: 5 weight transposes + x conversion, one dispatch -----------------
__global__ __launch_bounds__(256) void prep_all(
    const float* __restrict__ x,
    const float* __restrict__ Wq, const float* __restrict__ Wk,
    const float* __restrict__ Wv, const float* __restrict__ W1,
    const float* __restrict__ W2,
    u16* __restrict__ xb,
    u16* __restrict__ Wqkv, u16* __restrict__ W1T, u16* __restrict__ W2T)
{
  __shared__ float t[32][33];
  const int tx = threadIdx.x, ty = threadIdx.y;
  if (blockIdx.z == 5) {
    const int tid = ty * 32 + tx;
    const size_t base = ((size_t)(blockIdx.y * 32 + blockIdx.x)) * 8192;
    #pragma unroll
    for (int it = 0; it < 8; ++it) {
      size_t i = base + (size_t)(it * 256 + tid) * 4;
      float4 v = *(const float4*)(x + i);
      uint2 o;
      o.x = (u32)f2b(v.x) | ((u32)f2b(v.y) << 16);
      o.y = (u32)f2b(v.z) | ((u32)f2b(v.w) << 16);
      *(uint2*)(xb + i) = o;
    }
    return;
  }
  const float* W; u16* T;
  switch (blockIdx.z) {
    case 0: W = Wq; T = Wqkv;                   break;
    case 1: W = Wk; T = Wqkv + 1 * DIMN * DIMN; break;
    case 2: W = Wv; T = Wqkv + 2 * DIMN * DIMN; break;
    case 3: W = W1; T = W1T;                    break;
    default: W = W2; T = W2T;                   break;
  }
  int k0 = blockIdx.x * 32, n0 = blockIdx.y * 32;
  #pragma unroll
  for (int j = 0; j < 32; j += 8)
    t[ty + j][tx] = W[(size_t)(k0 + ty + j) * DIMN + n0 + tx];
  __syncthreads();
  #pragma unroll
  for (int j = 0; j < 32; j += 8)
    T[(size_t)(n0 + ty + j) * DIMN + k0 + tx] = f2b(t[tx][ty + j]);
}

// ---- MFMA GEMM: C[M,N] = A[M,K] * B^T  (B given as [N][K]) ------------------
// 128x128 tile, BK=64, 256 threads = 4 waves, wave tile 64x64 (4x4 of 16x16x32).
// Staging: global_load_lds width=16, XOR chunk swizzle (0 conflicts in K-loop).
// ALL epilogues route the C-tile through LDS (reusing the staging buffers) and
// store coalesced uint4 rows — measured r5->r6: this beat scalar stores on the
// V path by a wide margin; now applied uniformly.
// SWZ=1 (tall GEMMs): bm-band per XCD (id%8), n-major traversal within band.
// EPI: 3 = QKV routed (+bias; V segment stores VT[b][d][tok] transposed)
//      4 = +bias, GELU (tanh form), bf16
//      6 = plain bf16
template <int EPI, int SWZ>
__global__ __launch_bounds__(256) void gemm_bt(
    const u16* __restrict__ A, const u16* __restrict__ Bm,
    u16* __restrict__ Cb, u16* __restrict__ Cb2, u16* __restrict__ Cb3,
    const float* __restrict__ bias, const float* __restrict__ bias2,
    const float* __restrict__ bias3,
    int M, int N, int K, int ldc,
    size_t sA, size_t sB, size_t sC)
{
  __shared__ u16 smem[2 * 128 * 64];   // 32 KiB: As | Bs; reused by epilogue
  u16* As = smem;
  u16* Bs = smem + 128 * 64;

  const int tid = threadIdx.x;

  int bm0, bn0;
  if (SWZ == 1) {
    const int id   = blockIdx.y * gridDim.x + blockIdx.x;
    const int xcd  = id & 7;
    const int idx  = id >> 3;
    const int band = gridDim.x >> 3;          // bm rows per XCD
    bm0 = (xcd * band + idx % band) * 128;
    bn0 = (idx / band) * 128;
  } else {
    bm0 = blockIdx.x * 128;
    bn0 = blockIdx.y * 128;
  }

  A  += (size_t)blockIdx.z * sA;
  Bm += (size_t)blockIdx.z * sB;
  const int wave = tid >> 6, lane = tid & 63;
  const int wm   = (wave >> 1) * 64, wn = (wave & 1) * 64;
  const int l16  = lane & 15, quad = lane >> 4;

  f32x4 acc[4][4] = {};

  for (int k0 = 0; k0 < K; k0 += 64) {
    #pragma unroll
    for (int j = 0; j < 4; ++j) {
      const int c  = wave * 256 + j * 64 + lane;
      const int r  = c >> 3;
      const int cg = (c & 7) ^ (r & 7);
      const u16* gA = A  + (size_t)(bm0 + r) * K + k0 + cg * 8;
      const u16* gB = Bm + (size_t)(bn0 + r) * K + k0 + cg * 8;
      u16* lA = As + (wave * 4 + j) * 512;   // wave-uniform base, +lane*16B in HW
      u16* lB = Bs + (wave * 4 + j) * 512;
      __builtin_amdgcn_global_load_lds((const AS1 void*)gA, (AS3 void*)lA, 16, 0, 0);
      __builtin_amdgcn_global_load_lds((const AS1 void*)gB, (AS3 void*)lB, 16, 0, 0);
    }
    __syncthreads();

    #pragma unroll
    for (int kk = 0; kk < 64; kk += 32) {
      const int kc = kk >> 3;
      const int sw = l16 & 7;
      bf16x8 af[4], bfr[4];
      #pragma unroll
      for (int t = 0; t < 4; ++t) {
        const int row = wm + t * 16 + l16;
        af[t] = *(const bf16x8*)(&As[row * 64 + (((kc + quad) ^ sw) << 3)]);
      }
      #pragma unroll
      for (int t = 0; t < 4; ++t) {
        const int row = wn + t * 16 + l16;
        bfr[t] = *(const bf16x8*)(&Bs[row * 64 + (((kc + quad) ^ sw) << 3)]);
      }
      #pragma unroll
      for (int mt = 0; mt < 4; ++mt)
        #pragma unroll
        for (int nt = 0; nt < 4; ++nt)
          acc[mt][nt] = __builtin_amdgcn_mfma_f32_16x16x32_bf16(
              af[mt], bfr[nt], acc[mt][nt], 0, 0, 0);
    }
    __syncthreads();
  }

  // ---- epilogue: C/D layout col = lane&15, row = quad*4 + reg ----
  const int seg = bn0 >> 10;   // meaningful for EPI 3

  if (EPI == 3 && seg == 2) {
    // V segment: bias, LDS-transpose the 128x128 tile, store VT coalesced.
    #pragma unroll
    for (int mt = 0; mt < 4; ++mt) {
      const int tok_l0 = wm + mt * 16 + quad * 4;
      #pragma unroll
      for (int nt = 0; nt < 4; ++nt) {
        const int d_l = wn + nt * 16 + l16;
        const float bv = bias3[(bn0 & 1023) + d_l];
        ushort4 pk;
        pk.x = f2b(acc[mt][nt][0] + bv);
        pk.y = f2b(acc[mt][nt][1] + bv);
        pk.z = f2b(acc[mt][nt][2] + bv);
        pk.w = f2b(acc[mt][nt][3] + bv);
        const int addr = d_l * 128 +
            ((((tok_l0 >> 3) ^ (d_l & 7)) << 3) | (tok_l0 & 7));
        *(ushort4*)(&smem[addr]) = pk;
      }
    }
    __syncthreads();
    const int b_idx = bm0 >> 11;
    const int tok0  = bm0 & 2047;
    const int d0    = bn0 & 1023;
    u16* dst = Cb3 + (size_t)b_idx * DIMN * SEQ;
    #pragma unroll
    for (int p = 0; p < 8; ++p) {
      const int idx = p * 256 + tid;
      const int row = idx >> 4, c = idx & 15;
      uint4 v = *(const uint4*)(&smem[row * 128 + ((c ^ (row & 7)) << 3)]);
      *(uint4*)(&dst[(size_t)(d0 + row) * SEQ + tok0 + c * 8]) = v;
    }
    return;
  }

  // generic path: bias/activation in write phase, coalesced row stores
  u16* dst; const float* bp; int col0;
  if (EPI == 3) {
    dst = seg ? Cb2 : Cb;  bp = seg ? bias2 : bias;  col0 = bn0 & 1023;
  } else if (EPI == 4) {
    dst = Cb;  bp = bias;  col0 = bn0;
  } else {
    dst = Cb + (size_t)blockIdx.z * sC;  bp = nullptr;  col0 = bn0;
  }

  #pragma unroll
  for (int mt = 0; mt < 4; ++mt) {
    const int r0 = wm + mt * 16 + quad * 4;
    #pragma unroll
    for (int nt = 0; nt < 4; ++nt) {
      const int cl = wn + nt * 16 + l16;
      const float bv = (EPI == 6) ? 0.0f : bp[col0 + cl];
      #pragma unroll
      for (int r = 0; r < 4; ++r) {
        float v = acc[mt][nt][r] + bv;
        if (EPI == 4) v = gelu_fast(v);
        const int row  = r0 + r;
        const int addr = row * 128 + ((((cl >> 3) ^ (row & 7)) << 3) | (cl & 7));
        smem[addr] = f2b(v);
      }
    }
  }
  __syncthreads();
  #pragma unroll
  for (int p = 0; p < 8; ++p) {
    const int idx = p * 256 + tid;
    const int row = idx >> 4, c = idx & 15;
    uint4 v = *(const uint4*)(&smem[row * 128 + ((c ^ (row & 7)) << 3)]);
    *(uint4*)(&dst[(size_t)(bm0 + row) * ldc + col0 + c * 8]) = v;
  }
}

// ---- softmax: one row of 2048 per WAVE (bf16 in/out, scale 1/8) -------------
__global__ __launch_bounds__(256) void softmax_rows(const u16* __restrict__ Sc,
                                                    u16* __restrict__ P) {
  const int wave = threadIdx.x >> 6, lane = threadIdx.x & 63;
  const int row  = blockIdx.x * 4 + wave;
  const u16* s = Sc + (size_t)row * SEQ;
  u16*       p = P  + (size_t)row * SEQ;
  float v[32];
  #pragma unroll
  for (int k = 0; k < 4; ++k) {
    uint4 raw = *(const uint4*)(s + k * 512 + lane * 8);
    unpack8(raw, &v[k * 8]);
  }
  float mx = -1e30f;
  #pragma unroll
  for (int i = 0; i < 32; ++i) { v[i] *= 0.125f; mx = fmaxf(mx, v[i]); }
  mx = wave_max(mx);
  float sum = 0.0f;
  #pragma unroll
  for (int i = 0; i < 32; ++i) { v[i] = __expf(v[i] - mx); sum += v[i]; }
  sum = wave_sum(sum);
  float inv = 1.0f / sum;
  #pragma unroll
  for (int i = 0; i < 32; ++i) v[i] *= inv;
  #pragma unroll
  for (int k = 0; k < 4; ++k)
    *(uint4*)(p + k * 512 + lane * 8) = pack8(&v[k * 8]);
}

// ---- h = LN( LN(attn+x)*g_at+b_at + x )*g_ln+b_ln -> hres bf16 (row/wave) ---
__global__ __launch_bounds__(256) void ln1_fused(
    const u16* __restrict__ attn, const u16* __restrict__ xb,
    const float* __restrict__ g_at, const float* __restrict__ b_at,
    const float* __restrict__ g_ln, const float* __restrict__ b_ln,
    u16* __restrict__ hres)
{
  const int wave = threadIdx.x >> 6, lane = threadIdx.x & 63;
  const int row  = blockIdx.x * 4 + wave;
  const size_t base = (size_t)row * DIMN;
  const int c0 = lane * 8, c1 = 512 + lane * 8;

  float av[16], xr[16], y[16];
  unpack8(*(const uint4*)(attn + base + c0), &av[0]);
  unpack8(*(const uint4*)(attn + base + c1), &av[8]);
  unpack8(*(const uint4*)(xb + base + c0), &xr[0]);
  unpack8(*(const uint4*)(xb + base + c1), &xr[8]);

  float s = 0.0f, s2 = 0.0f;
  #pragma unroll
  for (int i = 0; i < 16; ++i) {
    y[i] = av[i] + xr[i];
    s += y[i]; s2 += y[i] * y[i];
  }
  s = wave_sum(s); s2 = wave_sum(s2);
  float m  = s * (1.0f / DIMN);
  float rs = rsqrtf(s2 * (1.0f / DIMN) - m * m + 1e-5f);

  float z[16];
  s = 0.0f; s2 = 0.0f;
  #pragma unroll
  for (int h = 0; h < 2; ++h) {
    const int c = h ? c1 : c0;
    float4 ga = *(const float4*)(g_at + c), gb = *(const float4*)(g_at + c + 4);
    float4 ba = *(const float4*)(b_at + c), bb = *(const float4*)(b_at + c + 4);
    const float* gp = (const float*)&ga; const float* gq = (const float*)&gb;
    const float* bp = (const float*)&ba; const float* bq = (const float*)&bb;
    #pragma unroll
    for (int i = 0; i < 4; ++i) {
      int j = h * 8 + i;
      float at = (y[j] - m) * rs * gp[i] + bp[i];
      z[j] = at + xr[j]; s += z[j]; s2 += z[j] * z[j];
    }
    #pragma unroll
    for (int i = 0; i < 4; ++i) {
      int j = h * 8 + 4 + i;
      float at = (y[j] - m) * rs * gq[i] + bq[i];
      z[j] = at + xr[j]; s += z[j]; s2 += z[j] * z[j];
    }
  }
  s = wave_sum(s); s2 = wave_sum(s2);
  float m2  = s * (1.0f / DIMN);
  float rs2 = rsqrtf(s2 * (1.0f / DIMN) - m2 * m2 + 1e-5f);

  float o[16];
  #pragma unroll
  for (int h = 0; h < 2; ++h) {
    const int c = h ? c1 : c0;
    float4 ga = *(const float4*)(g_ln + c), gb = *(const float4*)(g_ln + c + 4);
    float4 ba = *(const float4*)(b_ln + c), bb = *(const float4*)(b_ln + c + 4);
    const float* gp = (const float*)&ga; const float* gq = (const float*)&gb;
    const float* bp = (const float*)&ba; const float* bq = (const float*)&bb;
    #pragma unroll
    for (int i = 0; i < 4; ++i)
      o[h * 8 + i] = (z[h * 8 + i] - m2) * rs2 * gp[i] + bp[i];
    #pragma unroll
    for (int i = 0; i < 4; ++i)
      o[h * 8 + 4 + i] = (z[h * 8 + 4 + i] - m2) * rs2 * gq[i] + bq[i];
  }
  *(uint4*)(hres + base + c0) = pack8(&o[0]);
  *(uint4*)(hres + base + c1) = pack8(&o[8]);
}

// ---- out = LN(u + hres)*g_ln + b_ln  (bf16 in, f32 out), one row per wave ---
__global__ __launch_bounds__(256) void ln2_final(
    const u16* __restrict__ u, const u16* __restrict__ hres,
    const float* __restrict__ g, const float* __restrict__ bb,
    float* __restrict__ out)
{
  const int wave = threadIdx.x >> 6, lane = threadIdx.x & 63;
  const int row  = blockIdx.x * 4 + wave;
  const size_t base = (size_t)row * DIMN;
  const int c0 = lane * 8, c1 = 512 + lane * 8;

  float uv[16], hv[16], y[16];
  unpack8(*(const uint4*)(u + base + c0), &uv[0]);
  unpack8(*(const uint4*)(u + base + c1), &uv[8]);
  unpack8(*(const uint4*)(hres + base + c0), &hv[0]);
  unpack8(*(const uint4*)(hres + base + c1), &hv[8]);

  float s = 0.0f, s2 = 0.0f;
  #pragma unroll
  for (int i = 0; i < 16; ++i) {
    y[i] = uv[i] + hv[i];
    s += y[i]; s2 += y[i] * y[i];
  }
  s = wave_sum(s); s2 = wave_sum(s2);
  float m  = s * (1.0f / DIMN);
  float rs = rsqrtf(s2 * (1.0f / DIMN) - m * m + 1e-5f);

  #pragma unroll
  for (int h = 0; h < 2; ++h) {
    const int c = h ? c1 : c0;
    float4 ga = *(const float4*)(g + c),  gb2 = *(const float4*)(g + c + 4);
    float4 ba = *(const float4*)(bb + c), bb2 = *(const float4*)(bb + c + 4);
    const float* gp = (const float*)&ga;  const float* gq = (const float*)&gb2;
    const float* bp = (const float*)&ba;  const float* bq = (const float*)&bb2;
    float4 o1, o2;
    ((float*)&o1)[0] = (y[h*8+0] - m) * rs * gp[0] + bp[0];
    ((float*)&o1)[1] = (y[h*8+1] - m) * rs * gp[1] + bp[1];
    ((float*)&o1)[2] = (y[h*8+2] - m) * rs * gp[2] + bp[2];
    ((float*)&o1)[3] = (y[h*8+3] - m) * rs * gp[3] + bp[3];
    ((float*)&o2)[0] = (y[h*8+4] - m) * rs * gq[0] + bq[0];
    ((float*)&o2)[1] = (y[h*8+5] - m) * rs * gq[1] + bq[1];
    ((float*)&o2)[2] = (y[h*8+6] - m) * rs * gq[2] + bq[2];
    ((float*)&o2)[3] = (y[h*8+7] - m) * rs * gq[3] + bq[3];
    *(float4*)(out + base + c)     = o1;
    *(float4*)(out + base + c + 4) = o2;
  }
}

// ---- launch -----------------------------------------------------------------

extern "C" void kernel_launch(void* const* d_in, const int* in_sizes, int n_in,
                              void* d_out, int out_size, void* d_ws, size_t ws_size,
                              hipStream_t stream)
{
  const float* x    = (const float*)d_in[0];
  const float* Wq   = (const float*)d_in[1];
  const float* bq   = (const float*)d_in[2];
  const float* Wk   = (const float*)d_in[3];
  const float* bk   = (const float*)d_in[4];
  const float* Wv   = (const float*)d_in[5];
  const float* bv   = (const float*)d_in[6];
  const float* g_at = (const float*)d_in[7];
  const float* b_at = (const float*)d_in[8];
  const float* g_ln = (const float*)d_in[9];
  const float* b_ln = (const float*)d_in[10];
  const float* W1   = (const float*)d_in[11];
  const float* c1   = (const float*)d_in[12];
  const float* W2   = (const float*)d_in[13];
  const float* c2   = (const float*)d_in[14];
  float* out = (float*)d_out;

  // workspace layout (1 MiB units), peak 138 MiB:
  //   0..16   xb      (alive through ln1)
  //  16..18   W1T   18..20 W2T   20..26 WqkvT [3072][1024]
  //  26..42   Qb      (dead after scores)
  //  42..58   Kb      (dead after scores; tb alias for FFN mid)
  //  58..74   VT [b][d][tok]  (dead after PV; ub alias for FFN out)
  //  74..106  Sc bf16 (dead after softmax; attn 74..90, hres 90..106 alias)
  // 106..138  Pb bf16
  char* ws = (char*)d_ws;
  const size_t MB = 1u << 20;
  u16* xb    = (u16*)(ws + 0 * MB);
  u16* W1T   = (u16*)(ws + 16 * MB);
  u16* W2T   = (u16*)(ws + 18 * MB);
  u16* WqkvT = (u16*)(ws + 20 * MB);
  u16* Qb    = (u16*)(ws + 26 * MB);
  u16* Kb    = (u16*)(ws + 42 * MB);
  u16* VT    = (u16*)(ws + 58 * MB);
  u16* Sc    = (u16*)(ws + 74 * MB);
  u16* attn  = (u16*)(ws + 74 * MB);
  u16* hres  = (u16*)(ws + 90 * MB);
  u16* Pb    = (u16*)(ws + 106 * MB);
  u16* tb    = Kb;   // FFN mid, K dead
  u16* ub    = VT;   // FFN out, VT dead after PV

  // prep: x conversion + all weight transposes, one dispatch
  prep_all<<<dim3(32, 32, 6), dim3(32, 8), 0, stream>>>(
      x, Wq, Wk, Wv, W1, W2, xb, WqkvT, W1T, W2T);

  // fused QKV projection: [8192,1024] @ [3072,1024]^T, bm-band swizzle.
  gemm_bt<3, 1><<<dim3(64, 24), 256, 0, stream>>>(
      xb, WqkvT, Qb, Kb, VT, bq, bk, bv,
      TOKS, 3 * DIMN, DIMN, DIMN, 0, 0, 0);

  // scores (bf16 out), batched over grid.z, natural order
  gemm_bt<6, 0><<<dim3(16, 16, NBAT), 256, 0, stream>>>(
      Qb, Kb, Sc, nullptr, nullptr, nullptr, nullptr, nullptr,
      SEQ, SEQ, DIMN, SEQ,
      (size_t)SEQ * DIMN, (size_t)SEQ * DIMN, (size_t)SEQ * SEQ);
  softmax_rows<<<TOKS / 4, 256, 0, stream>>>(Sc, Pb);
  gemm_bt<6, 0><<<dim3(16, 8, NBAT), 256, 0, stream>>>(
      Pb, VT, attn, nullptr, nullptr, nullptr, nullptr, nullptr,
      SEQ, DIMN, SEQ, DIMN,
      (size_t)SEQ * SEQ, (size_t)DIMN * SEQ, (size_t)SEQ * DIMN);

  // h = LN(LN(attn+x)+x) -> hres bf16
  ln1_fused<<<TOKS / 4, 256, 0, stream>>>(attn, xb, g_at, b_at, g_ln, b_ln, hres);

  // FFN (bm-band swizzle)
  gemm_bt<4, 1><<<dim3(64, 8), 256, 0, stream>>>(
      hres, W1T, tb, nullptr, nullptr, c1, nullptr, nullptr,
      TOKS, DIMN, DIMN, DIMN, 0, 0, 0);
  gemm_bt<4, 1><<<dim3(64, 8), 256, 0, stream>>>(
      tb, W2T, ub, nullptr, nullptr, c2, nullptr, nullptr,
      TOKS, DIMN, DIMN, DIMN, 0, 0, 0);

  // out = LN(u + h)
  ln2_final<<<TOKS / 4, 256, 0, stream>>>(ub, hres, g_ln, b_ln, out);
}